// Round 4
// baseline (274.291 us; speedup 1.0000x reference)
//
#include <hip/hip_runtime.h>

#define BB 2
#define NPTS 16384
#define NQ (2*BB*NPTS)        // 65536 query work-items (2 directions x B x N)

// ws layout (CH = CHUNKS):
//   float4 cand[2][BB][NPTS]   : 1 MB  (slot 0: xyz2 points, slot 1: xyz1 points; w = |p|^2)
//   float  pd[CH][NQ]          : CH*256 KB   (min distance per chunk, round-2-exact key)
//   int    pi[CH][NQ]          : CH*256 KB   (argmin per chunk, global candidate index)

__global__ __launch_bounds__(256) void prep_kernel(
    const float* __restrict__ xyz1, const float* __restrict__ xyz2,
    float4* __restrict__ cand)
{
    int t = blockIdx.x * 256 + threadIdx.x;   // 0..65535
    int dir = t >> 15;                        // 0: xyz2 points, 1: xyz1 points
    int rem = t & 32767;                      // b*NPTS + j
    const float* src = dir ? xyz1 : xyz2;
    float x = src[rem*3+0];
    float y = src[rem*3+1];
    float z = src[rem*3+2];
    // match numpy sum(b*b,-1): (x*x + y*y) + z*z, no contraction
    float sq = __fadd_rn(__fadd_rn(__fmul_rn(x,x), __fmul_rn(y,y)), __fmul_rn(z,z));
    cand[t] = make_float4(x, y, z, sq);
}

// 8 queries per thread, group-min (G=32) + rescan argmin, EXACT round-2 key:
//   t = fma(az,cz, fma(ay,cy, ax*cx));  d = fma(-2, t, rn(asq+bsq))
// Grid: (NQ/2048, CH). blockIdx.y = candidate chunk.
template<int CH>
__global__ __launch_bounds__(256) void nn_partial8(
    const float4* __restrict__ cand,
    float* __restrict__ pd, int* __restrict__ pi)
{
    constexpr int CLEN = NPTS / CH;
    constexpr int G    = 32;
    constexpr int NGRP = CLEN / G;
    const int bx    = blockIdx.x;          // 0..31
    const int chunk = blockIdx.y;          // 0..CH-1
    const int dir   = bx >> 4;             // 16 blocks per direction
    const int q15b  = (bx & 15) << 11;     // within-direction query base (2048-aligned)
    const int bb    = (q15b >> 14) & 1;    // batch index

    const float4* qt = cand + ((dir ^ 1) << 15) + q15b;                  // queries
    const float4* cp = cand + (dir << 15) + (bb << 14) + chunk * CLEN;   // candidates

    const int t = threadIdx.x;

    float ax[8], ay[8], az[8], aw[8], bd[8];
    int gbest[8];
    #pragma unroll
    for (int k = 0; k < 8; ++k) {
        float4 qv = qt[t + k*256];
        ax[k] = qv.x; ay[k] = qv.y; az[k] = qv.z; aw[k] = qv.w;
        bd[k] = __builtin_inff(); gbest[k] = 0;
    }

    for (int g = 0; g < NGRP; ++g) {
        float gacc[8];
        #pragma unroll
        for (int k = 0; k < 8; ++k) gacc[k] = __builtin_inff();
        #pragma unroll 2
        for (int j = 0; j < G; j += 4) {
            float4 c0 = cp[g*G + j+0];
            float4 c1 = cp[g*G + j+1];
            float4 c2 = cp[g*G + j+2];
            float4 c3 = cp[g*G + j+3];
            #pragma unroll
            for (int k = 0; k < 8; ++k) {
                float t0 = fmaf(az[k], c0.z, fmaf(ay[k], c0.y, __fmul_rn(ax[k], c0.x)));
                float d0 = fmaf(-2.0f, t0, __fadd_rn(aw[k], c0.w));
                float t1 = fmaf(az[k], c1.z, fmaf(ay[k], c1.y, __fmul_rn(ax[k], c1.x)));
                float d1 = fmaf(-2.0f, t1, __fadd_rn(aw[k], c1.w));
                float t2 = fmaf(az[k], c2.z, fmaf(ay[k], c2.y, __fmul_rn(ax[k], c2.x)));
                float d2 = fmaf(-2.0f, t2, __fadd_rn(aw[k], c2.w));
                float t3 = fmaf(az[k], c3.z, fmaf(ay[k], c3.y, __fmul_rn(ax[k], c3.x)));
                float d3 = fmaf(-2.0f, t3, __fadd_rn(aw[k], c3.w));
                // v_min3-fusable tree; fminf returns an input bitwise
                gacc[k] = fminf(fminf(d0, d1), fminf(fminf(d2, d3), gacc[k]));
            }
        }
        #pragma unroll
        for (int k = 0; k < 8; ++k) {
            bool imp = gacc[k] < bd[k];          // strict: earlier group wins ties
            bd[k]    = imp ? gacc[k] : bd[k];
            gbest[k] = imp ? g       : gbest[k];
        }
    }

    // Rescan winning group: first j whose recomputed (identical) key == bd.
    const int qid0 = (dir << 15) + q15b + t;
    #pragma unroll
    for (int k = 0; k < 8; ++k) {
        const float4* rp = cp + gbest[k] * G;
        int idx = 0;
        for (int j = G - 1; j >= 0; --j) {       // backward: last update = first match
            float4 c = rp[j];
            float tt = fmaf(az[k], c.z, fmaf(ay[k], c.y, __fmul_rn(ax[k], c.x)));
            float dd = fmaf(-2.0f, tt, __fadd_rn(aw[k], c.w));
            idx = (dd != bd[k]) ? idx : j;
        }
        int qid = qid0 + k*256;
        pd[chunk*NQ + qid] = bd[k];
        pi[chunk*NQ + qid] = chunk*CLEN + gbest[k]*G + idx;
    }
}

template<int CH>
__global__ __launch_bounds__(256) void nn_merge(
    const float* __restrict__ pd, const int* __restrict__ pi,
    float* __restrict__ out)
{
    int qid = blockIdx.x * 256 + threadIdx.x;
    float bd = pd[qid];
    int   bi = pi[qid];
    #pragma unroll
    for (int c = 1; c < CH; ++c) {
        float d = pd[c*NQ + qid];
        int   i = pi[c*NQ + qid];
        if (d < bd || (d == bd && i < bi)) { bd = d; bi = i; }  // lower index wins ties
    }
    int dir = qid >> 15;
    int q15 = qid & 32767;
    // out: [dist1 (32768) | dist2 (32768) | idx1 (32768) | idx2 (32768)]
    int off = dir ? 32768 : 0;
    out[off + q15]         = bd;
    out[65536 + off + q15] = (float)bi;
}

// Ultimate fallback (no ws): fused, recomputes bsq in-loop.
__global__ __launch_bounds__(256) void nn_full(
    const float* __restrict__ xyz1, const float* __restrict__ xyz2,
    float* __restrict__ out)
{
    int qid = blockIdx.x * 256 + threadIdx.x;
    int dir = qid >> 15;
    int q15 = qid & 32767;
    const float* qsrc = dir ? xyz2 : xyz1;
    float ax = qsrc[q15*3+0];
    float ay = qsrc[q15*3+1];
    float az = qsrc[q15*3+2];
    float asq = __fadd_rn(__fadd_rn(__fmul_rn(ax,ax), __fmul_rn(ay,ay)), __fmul_rn(az,az));
    const float* cp = (dir ? xyz1 : xyz2) + (size_t)(q15 & NPTS) * 3;

    float bd = 3.402823466e+38f; int bi = 0;
    for (int j = 0; j < NPTS; ++j) {
        float bx = cp[3*j+0], by = cp[3*j+1], bz = cp[3*j+2];
        float bsq = __fadd_rn(__fadd_rn(__fmul_rn(bx,bx), __fmul_rn(by,by)), __fmul_rn(bz,bz));
        float tt = fmaf(az, bz, fmaf(ay, by, __fmul_rn(ax, bx)));
        float d = fmaf(-2.0f, tt, __fadd_rn(asq, bsq));
        if (d < bd) { bd = d; bi = j; }
    }
    int off = dir ? 32768 : 0;
    out[off + q15]         = bd;
    out[65536 + off + q15] = (float)bi;
}

extern "C" void kernel_launch(void* const* d_in, const int* in_sizes, int n_in,
                              void* d_out, int out_size, void* d_ws, size_t ws_size,
                              hipStream_t stream) {
    const float* xyz1 = (const float*)d_in[0];
    const float* xyz2 = (const float*)d_in[1];
    float* out = (float*)d_out;

    size_t cand_bytes = (size_t)NQ * 16;  // 1 MB

    auto run = [&](auto ch_const) {
        constexpr int CH = decltype(ch_const)::value;
        float4* cand = (float4*)d_ws;
        float*  pd   = (float*)((char*)d_ws + cand_bytes);
        int*    pi   = (int*)((char*)d_ws + cand_bytes + (size_t)CH*NQ*4);
        prep_kernel<<<NQ/256, 256, 0, stream>>>(xyz1, xyz2, cand);
        dim3 grid(NQ/2048, CH);
        nn_partial8<CH><<<grid, 256, 0, stream>>>(cand, pd, pi);
        nn_merge<CH><<<NQ/256, 256, 0, stream>>>(pd, pi, out);
    };

    size_t need32 = cand_bytes + (size_t)32*NQ*8;  // 17 MB
    size_t need8  = cand_bytes + (size_t)8*NQ*8;   // 5 MB
    if (d_ws != nullptr && ws_size >= need32) {
        run(std::integral_constant<int, 32>{});
    } else if (d_ws != nullptr && ws_size >= need8) {
        run(std::integral_constant<int, 8>{});
    } else {
        nn_full<<<NQ/256, 256, 0, stream>>>(xyz1, xyz2, out);
    }
}

// Round 5
// 193.446 us; speedup vs baseline: 1.4179x; 1.4179x over previous
//
#include <hip/hip_runtime.h>

#define BB 2
#define NPTS 16384
#define NQ (2*BB*NPTS)        // 65536 query work-items (2 directions x B x N)

// ws layout (CH = CHUNKS):
//   float4 cand[2][BB][NPTS]   : 1 MB  (slot 0: xyz2 points, slot 1: xyz1 points; w = |p|^2)
//   float  pd[CH][NQ]          : CH*256 KB   (min distance per chunk, round-2-exact key)
//   int    pi[CH][NQ]          : CH*256 KB   (argmin per chunk, global candidate index)

__global__ __launch_bounds__(256) void prep_kernel(
    const float* __restrict__ xyz1, const float* __restrict__ xyz2,
    float4* __restrict__ cand)
{
    int t = blockIdx.x * 256 + threadIdx.x;   // 0..65535
    int dir = t >> 15;                        // 0: xyz2 points, 1: xyz1 points
    int rem = t & 32767;                      // b*NPTS + j
    const float* src = dir ? xyz1 : xyz2;
    float x = src[rem*3+0];
    float y = src[rem*3+1];
    float z = src[rem*3+2];
    // match numpy sum(b*b,-1): (x*x + y*y) + z*z, no contraction
    float sq = __fadd_rn(__fadd_rn(__fmul_rn(x,x), __fmul_rn(y,y)), __fmul_rn(z,z));
    cand[t] = make_float4(x, y, z, sq);
}

// 4 queries per thread (grid 64 x CH = 2048 blocks -> full residency),
// group-min (G=32) + rescan argmin, EXACT round-2 key:
//   t = fma(az,cz, fma(ay,cy, ax*cx));  d = fma(-2, t, rn(asq+bsq))
template<int CH>
__global__ __launch_bounds__(256) void nn_partial4g(
    const float4* __restrict__ cand,
    float* __restrict__ pd, int* __restrict__ pi)
{
    constexpr int CLEN = NPTS / CH;
    constexpr int G    = 32;
    constexpr int NGRP = CLEN / G;
    const int bx    = blockIdx.x;          // 0..63
    const int chunk = blockIdx.y;          // 0..CH-1
    const int dir   = bx >> 5;             // 32 blocks per direction
    const int q15b  = (bx & 31) << 10;     // within-direction query base (1024-aligned)
    const int bb    = (q15b >> 14) & 1;    // batch index

    const float4* qt = cand + ((dir ^ 1) << 15) + q15b;                  // queries
    const float4* cp = cand + (dir << 15) + (bb << 14) + chunk * CLEN;   // candidates

    const int t = threadIdx.x;

    float ax[4], ay[4], az[4], aw[4], bd[4];
    int gbest[4];
    #pragma unroll
    for (int k = 0; k < 4; ++k) {
        float4 qv = qt[t + k*256];
        ax[k] = qv.x; ay[k] = qv.y; az[k] = qv.z; aw[k] = qv.w;
        bd[k] = __builtin_inff(); gbest[k] = 0;
    }

    for (int g = 0; g < NGRP; ++g) {
        float gacc[4];
        #pragma unroll
        for (int k = 0; k < 4; ++k) gacc[k] = __builtin_inff();
        #pragma unroll 2
        for (int j = 0; j < G; j += 4) {
            float4 c0 = cp[g*G + j+0];
            float4 c1 = cp[g*G + j+1];
            float4 c2 = cp[g*G + j+2];
            float4 c3 = cp[g*G + j+3];
            #pragma unroll
            for (int k = 0; k < 4; ++k) {
                float t0 = fmaf(az[k], c0.z, fmaf(ay[k], c0.y, __fmul_rn(ax[k], c0.x)));
                float d0 = fmaf(-2.0f, t0, __fadd_rn(aw[k], c0.w));
                float t1 = fmaf(az[k], c1.z, fmaf(ay[k], c1.y, __fmul_rn(ax[k], c1.x)));
                float d1 = fmaf(-2.0f, t1, __fadd_rn(aw[k], c1.w));
                float t2 = fmaf(az[k], c2.z, fmaf(ay[k], c2.y, __fmul_rn(ax[k], c2.x)));
                float d2 = fmaf(-2.0f, t2, __fadd_rn(aw[k], c2.w));
                float t3 = fmaf(az[k], c3.z, fmaf(ay[k], c3.y, __fmul_rn(ax[k], c3.x)));
                float d3 = fmaf(-2.0f, t3, __fadd_rn(aw[k], c3.w));
                // v_min3-fusable tree; fminf returns an input bitwise
                gacc[k] = fminf(fminf(d0, d1), fminf(fminf(d2, d3), gacc[k]));
            }
        }
        #pragma unroll
        for (int k = 0; k < 4; ++k) {
            bool imp = gacc[k] < bd[k];          // strict: earlier group wins ties
            bd[k]    = imp ? gacc[k] : bd[k];
            gbest[k] = imp ? g       : gbest[k];
        }
    }

    // Rescan winning group: first j whose recomputed (identical) key == bd.
    const int qid0 = (dir << 15) + q15b + t;
    #pragma unroll
    for (int k = 0; k < 4; ++k) {
        const float4* rp = cp + gbest[k] * G;
        int idx = 0;
        #pragma unroll 4
        for (int j = G - 1; j >= 0; --j) {       // backward: last update = first match
            float4 c = rp[j];
            float tt = fmaf(az[k], c.z, fmaf(ay[k], c.y, __fmul_rn(ax[k], c.x)));
            float dd = fmaf(-2.0f, tt, __fadd_rn(aw[k], c.w));
            idx = (dd != bd[k]) ? idx : j;
        }
        int qid = qid0 + k*256;
        pd[chunk*NQ + qid] = bd[k];
        pi[chunk*NQ + qid] = chunk*CLEN + gbest[k]*G + idx;
    }
}

template<int CH>
__global__ __launch_bounds__(256) void nn_merge(
    const float* __restrict__ pd, const int* __restrict__ pi,
    float* __restrict__ out)
{
    int qid = blockIdx.x * 256 + threadIdx.x;
    float bd = pd[qid];
    int   bi = pi[qid];
    #pragma unroll
    for (int c = 1; c < CH; ++c) {
        float d = pd[c*NQ + qid];
        int   i = pi[c*NQ + qid];
        if (d < bd || (d == bd && i < bi)) { bd = d; bi = i; }  // lower index wins ties
    }
    int dir = qid >> 15;
    int q15 = qid & 32767;
    // out: [dist1 (32768) | dist2 (32768) | idx1 (32768) | idx2 (32768)]
    int off = dir ? 32768 : 0;
    out[off + q15]         = bd;
    out[65536 + off + q15] = (float)bi;
}

// Ultimate fallback (no ws): fused, recomputes bsq in-loop.
__global__ __launch_bounds__(256) void nn_full(
    const float* __restrict__ xyz1, const float* __restrict__ xyz2,
    float* __restrict__ out)
{
    int qid = blockIdx.x * 256 + threadIdx.x;
    int dir = qid >> 15;
    int q15 = qid & 32767;
    const float* qsrc = dir ? xyz2 : xyz1;
    float ax = qsrc[q15*3+0];
    float ay = qsrc[q15*3+1];
    float az = qsrc[q15*3+2];
    float asq = __fadd_rn(__fadd_rn(__fmul_rn(ax,ax), __fmul_rn(ay,ay)), __fmul_rn(az,az));
    const float* cp = (dir ? xyz1 : xyz2) + (size_t)(q15 & NPTS) * 3;

    float bd = 3.402823466e+38f; int bi = 0;
    for (int j = 0; j < NPTS; ++j) {
        float bx = cp[3*j+0], by = cp[3*j+1], bz = cp[3*j+2];
        float bsq = __fadd_rn(__fadd_rn(__fmul_rn(bx,bx), __fmul_rn(by,by)), __fmul_rn(bz,bz));
        float tt = fmaf(az, bz, fmaf(ay, by, __fmul_rn(ax, bx)));
        float d = fmaf(-2.0f, tt, __fadd_rn(asq, bsq));
        if (d < bd) { bd = d; bi = j; }
    }
    int off = dir ? 32768 : 0;
    out[off + q15]         = bd;
    out[65536 + off + q15] = (float)bi;
}

extern "C" void kernel_launch(void* const* d_in, const int* in_sizes, int n_in,
                              void* d_out, int out_size, void* d_ws, size_t ws_size,
                              hipStream_t stream) {
    const float* xyz1 = (const float*)d_in[0];
    const float* xyz2 = (const float*)d_in[1];
    float* out = (float*)d_out;

    size_t cand_bytes = (size_t)NQ * 16;  // 1 MB

    auto run = [&](auto ch_const) {
        constexpr int CH = decltype(ch_const)::value;
        float4* cand = (float4*)d_ws;
        float*  pd   = (float*)((char*)d_ws + cand_bytes);
        int*    pi   = (int*)((char*)d_ws + cand_bytes + (size_t)CH*NQ*4);
        prep_kernel<<<NQ/256, 256, 0, stream>>>(xyz1, xyz2, cand);
        dim3 grid(64, CH);
        nn_partial4g<CH><<<grid, 256, 0, stream>>>(cand, pd, pi);
        nn_merge<CH><<<NQ/256, 256, 0, stream>>>(pd, pi, out);
    };

    size_t need32 = cand_bytes + (size_t)32*NQ*8;  // 17 MB
    size_t need8  = cand_bytes + (size_t)8*NQ*8;   // 5 MB
    if (d_ws != nullptr && ws_size >= need32) {
        run(std::integral_constant<int, 32>{});
    } else if (d_ws != nullptr && ws_size >= need8) {
        run(std::integral_constant<int, 8>{});
    } else {
        nn_full<<<NQ/256, 256, 0, stream>>>(xyz1, xyz2, out);
    }
}